// Round 1
// 2964.283 us; speedup vs baseline: 1.0846x; 1.0846x over previous
//
#include <hip/hip_runtime.h>

typedef unsigned short u16;
typedef __bf16 bf16x8 __attribute__((ext_vector_type(8)));
typedef float f32x4 __attribute__((ext_vector_type(4)));

typedef const __attribute__((address_space(1))) void* gp1;
typedef __attribute__((address_space(3))) void* lp3;

__device__ __forceinline__ float bf2f(u16 u){
    union { unsigned int i; float f; } v; v.i = ((unsigned int)u) << 16; return v.f;
}
__device__ __forceinline__ u16 f2bf(float f){
    union { float f; unsigned int i; } v; v.f = f;
    unsigned int u = v.i;
    return (u16)((u + 0x7FFFu + ((u >> 16) & 1u)) >> 16);
}

// async global->LDS, 16B per lane. LDS dest must be wave-uniform base; HW adds lane*16.
__device__ __forceinline__ void gload16(const u16* g, const u16* l){
    __builtin_amdgcn_global_load_lds((gp1)(uintptr_t)g, (lp3)(uintptr_t)l, 16, 0, 0);
}

// block-wide sum for blockDim == 256 (4 waves)
__device__ __forceinline__ float blockSum(float v){
    #pragma unroll
    for (int off = 32; off; off >>= 1) v += __shfl_xor(v, off, 64);
    __shared__ float sm[4];
    const int w = threadIdx.x >> 6;
    __syncthreads();
    if ((threadIdx.x & 63) == 0) sm[w] = v;
    __syncthreads();
    return sm[0] + sm[1] + sm[2] + sm[3];
}

// fp32 -> bf16 elementwise (weights, once per launch). n multiple of 8.
__global__ __launch_bounds__(256)
void cvt_k(const float* __restrict__ in, u16* __restrict__ out, long long n)
{
    const long long stride = (long long)gridDim.x * 256 * 8;
    for (long long i = ((long long)blockIdx.x * 256 + threadIdx.x) * 8; i < n; i += stride) {
        float4 a = *(const float4*)(in + i);
        float4 b = *(const float4*)(in + i + 4);
        uint4 o;
        o.x = (unsigned)f2bf(a.x) | ((unsigned)f2bf(a.y) << 16);
        o.y = (unsigned)f2bf(a.z) | ((unsigned)f2bf(a.w) << 16);
        o.z = (unsigned)f2bf(b.x) | ((unsigned)f2bf(b.y) << 16);
        o.w = (unsigned)f2bf(b.z) | ((unsigned)f2bf(b.w) << 16);
        *(uint4*)(out + i) = o;
    }
}

// partial sums of image_embs over rows: grid (8*32), 18 rows each
__global__ __launch_bounds__(256)
void img_mean_k(const float* __restrict__ img, float* __restrict__ part)
{
    const int b = blockIdx.x >> 5, c = blockIdx.x & 31;
    const int t = threadIdx.x;
    const float* p = img + ((size_t)b * 576 + (size_t)c * 18) * 1024 + t * 4;
    float4 s = make_float4(0.f, 0.f, 0.f, 0.f);
    #pragma unroll
    for (int r = 0; r < 18; r++) {
        float4 v = *(const float4*)(p + (size_t)r * 1024);
        s.x += v.x; s.y += v.y; s.z += v.z; s.w += v.w;
    }
    *(float4*)(part + (size_t)blockIdx.x * 1024 + t * 4) = s;
}

// ---------------------------------------------------------------------------
// m97-structure GEMM: tile TM x 128, BK=64, global_load_lds staging, bf16 A & W.
// M may be non-multiple of TM (row-clamped staging; epilogue masks). N must be
// a multiple of 128 at launch (kept checked anyway). K multiple of 64.
// EPI: 0 bf16 +bias | 2 bf16 transposed +bias | 3 fp32 RMW += ls*(acc+bias)
//      4 bf16 exact-GELU +bias
// ---------------------------------------------------------------------------
template<int EPI, int TM>
__global__ __launch_bounds__(256)
void gemm_big(const u16* __restrict__ A, long long a_zo, long long a_zi, int lda,
              const u16* __restrict__ W, long long w_zo, long long w_zi, int ldw,
              void* __restrict__ Cv, long long c_zo, long long c_zi, int ldc,
              const float* __restrict__ bias, long long b_zo,
              const float* __restrict__ ls, long long ls_zo,
              int M, int N, int K, int Zi)
{
    constexpr int MI = TM / 32;          // 16x16 A-fragments per wave in M
    __shared__ u16 As[TM * 64];
    __shared__ u16 Ws[128 * 64];
    const int z  = blockIdx.z;
    const int zo = z / Zi, zi = z - zo * Zi;
    const u16* Az = A + (long long)zo * a_zo + (long long)zi * a_zi;
    const u16* Wz = W + (long long)zo * w_zo + (long long)zi * w_zi;
    const int m0 = blockIdx.y * TM, n0 = blockIdx.x * 128;
    const int t = threadIdx.x;
    const int lane = t & 63, wid = t >> 6;
    const int wm = (wid >> 1) * (TM / 2), wn = (wid & 1) * 64;
    const int qd = lane >> 4, ml = lane & 15;
    // staging: thread t covers row t>>3 (0..31 per issue), 8 elems at (t&7)*8.
    // matches HW lane->LDS mapping: base + lane*16B == row(lane>>3), col(lane&7)*8
    const int srow = t >> 3, scol = (t & 7) * 8;

    f32x4 acc[MI][4];
    #pragma unroll
    for (int i = 0; i < MI; i++)
        #pragma unroll
        for (int j = 0; j < 4; j++) acc[i][j] = (f32x4){0.f, 0.f, 0.f, 0.f};

    int arow[MI];
    #pragma unroll
    for (int i = 0; i < MI; i++) {
        int r = m0 + i * 32 + srow; arow[i] = (r < M) ? r : (M - 1);
    }
    int wrow[4];
    #pragma unroll
    for (int i = 0; i < 4; i++) {
        int r = n0 + i * 32 + srow; wrow[i] = (r < N) ? r : (N - 1);
    }

    for (int k0 = 0; k0 < K; k0 += 64) {
        #pragma unroll
        for (int i = 0; i < MI; i++)
            gload16(Az + (size_t)arow[i] * lda + k0 + scol, &As[(i * 32 + wid * 8) * 64]);
        #pragma unroll
        for (int i = 0; i < 4; i++)
            gload16(Wz + (size_t)wrow[i] * ldw + k0 + scol, &Ws[(i * 32 + wid * 8) * 64]);
        __syncthreads();   // compiler drains vmcnt before s_barrier
        #pragma unroll
        for (int kk = 0; kk < 64; kk += 32) {
            bf16x8 af[MI], bfr[4];
            #pragma unroll
            for (int i = 0; i < MI; i++)
                af[i] = __builtin_bit_cast(bf16x8, *(const uint4*)&As[(wm + 16*i + ml) * 64 + kk + qd * 8]);
            #pragma unroll
            for (int j = 0; j < 4; j++)
                bfr[j] = __builtin_bit_cast(bf16x8, *(const uint4*)&Ws[(wn + 16*j + ml) * 64 + kk + qd * 8]);
            #pragma unroll
            for (int i = 0; i < MI; i++)
                #pragma unroll
                for (int j = 0; j < 4; j++)
                    acc[i][j] = __builtin_amdgcn_mfma_f32_16x16x32_bf16(af[i], bfr[j], acc[i][j], 0, 0, 0);
        }
        __syncthreads();
    }

    const float* bz = bias ? bias + (long long)zo * b_zo : nullptr;
    const float* lz = (EPI == 3) ? ls + (long long)zo * ls_zo : nullptr;
    const long long coff = (long long)zo * c_zo + (long long)zi * c_zi;

    #pragma unroll
    for (int i = 0; i < MI; i++) {
        #pragma unroll
        for (int j = 0; j < 4; j++) {
            const int nn = n0 + wn + 16 * j + ml;
            if (nn >= N) continue;
            const float bv = bz ? bz[nn] : 0.f;
            if (EPI == 2) {
                const int mmb = m0 + wm + 16 * i + qd * 4;
                u16* C = (u16*)Cv + coff + (size_t)nn * ldc + mmb;
                if (mmb + 3 < M) {
                    u16 tmp[4];
                    #pragma unroll
                    for (int r = 0; r < 4; r++) tmp[r] = f2bf(acc[i][j][r] + bv);
                    *(uint2*)C = make_uint2((unsigned)tmp[0] | ((unsigned)tmp[1] << 16),
                                            (unsigned)tmp[2] | ((unsigned)tmp[3] << 16));
                } else {
                    #pragma unroll
                    for (int r = 0; r < 4; r++)
                        if (mmb + r < M) C[r] = f2bf(acc[i][j][r] + bv);
                }
            } else {
                const float lsv = (EPI == 3) ? lz[nn] : 0.f;
                #pragma unroll
                for (int r = 0; r < 4; r++) {
                    const int mm = m0 + wm + 16 * i + qd * 4 + r;
                    if (mm >= M) continue;
                    float v = acc[i][j][r];
                    if (EPI == 0) {
                        ((u16*)Cv + coff)[(size_t)mm * ldc + nn] = f2bf(v + bv);
                    } else if (EPI == 3) {
                        float* C = (float*)Cv + coff;
                        const size_t idx = (size_t)mm * ldc + nn;
                        C[idx] = C[idx] + lsv * (v + bv);
                    } else { // EPI == 4
                        float x = v + bv;
                        float g = 0.5f * x * (1.f + erff(x * 0.70710678118654752f));
                        ((u16*)Cv + coff)[(size_t)mm * ldc + nn] = f2bf(g);
                    }
                }
            }
        }
    }
}

// ---------------------------------------------------------------------------
// Legacy 64x64 GEMM — kept for the small attention GEMMs (S = QK^T, AO = P@V).
// ---------------------------------------------------------------------------
template<int EPI, int WF32>
__global__ __launch_bounds__(256)
void gemm_k(const u16* __restrict__ A, long long a_zo, long long a_zi, int lda,
            const void* __restrict__ W, long long w_zo, long long w_zi, int ldw,
            void* __restrict__ Cv, long long c_zo, long long c_zi, int ldc,
            const float* __restrict__ bias, long long b_zo,
            const float* __restrict__ ls, long long ls_zo,
            int M, int N, int K, int Zi)
{
    __shared__ u16 As[64][72];
    __shared__ u16 Ws[64][72];
    const int z  = blockIdx.z;
    const int zo = z / Zi, zi = z - zo * Zi;
    const u16* Az = A + (long long)zo * a_zo + (long long)zi * a_zi;
    const long long wbase = (long long)zo * w_zo + (long long)zi * w_zi;
    const int m0 = blockIdx.y * 64, n0 = blockIdx.x * 64;
    const int t = threadIdx.x;
    const int lrow = t >> 2, lcol = (t & 3) * 16;
    const int lane = t & 63, wid = t >> 6;
    const int wm = (wid >> 1) * 32, wn = (wid & 1) * 32;
    const int qd = lane >> 4, ml = lane & 15;

    f32x4 acc[2][2];
    #pragma unroll
    for (int i = 0; i < 2; i++)
        #pragma unroll
        for (int j = 0; j < 2; j++) acc[i][j] = (f32x4){0.f, 0.f, 0.f, 0.f};

    const bool arv = (m0 + lrow) < M;
    const bool wrv = (n0 + lrow) < N;
    const u16* ap = Az + (size_t)(m0 + lrow) * lda + lcol;

    for (int k0 = 0; k0 < K; k0 += 64) {
        {
            uint4 av0 = make_uint4(0u,0u,0u,0u), av1 = make_uint4(0u,0u,0u,0u);
            if (arv && (k0 + lcol) < K) {
                av0 = *(const uint4*)(ap + k0);
                av1 = *(const uint4*)(ap + k0 + 8);
            }
            *(uint4*)&As[lrow][lcol]     = av0;
            *(uint4*)&As[lrow][lcol + 8] = av1;
        }
        if (WF32) {
            const float* wp = (const float*)W + wbase + (size_t)(n0 + lrow) * ldw + lcol;
            const bool ok = wrv && (k0 + lcol) < K;
            u16 tmp[16];
            #pragma unroll
            for (int c = 0; c < 16; c += 4) {
                float4 f = make_float4(0.f,0.f,0.f,0.f);
                if (ok) f = *(const float4*)(wp + k0 + c);
                tmp[c+0] = f2bf(f.x); tmp[c+1] = f2bf(f.y);
                tmp[c+2] = f2bf(f.z); tmp[c+3] = f2bf(f.w);
            }
            unsigned pk[8];
            #pragma unroll
            for (int c = 0; c < 8; c++)
                pk[c] = (unsigned)tmp[2*c] | ((unsigned)tmp[2*c+1] << 16);
            *(uint4*)&Ws[lrow][lcol]     = make_uint4(pk[0],pk[1],pk[2],pk[3]);
            *(uint4*)&Ws[lrow][lcol + 8] = make_uint4(pk[4],pk[5],pk[6],pk[7]);
        } else {
            const u16* wp = (const u16*)W + wbase + (size_t)(n0 + lrow) * ldw + lcol;
            uint4 wv0 = make_uint4(0u,0u,0u,0u), wv1 = make_uint4(0u,0u,0u,0u);
            if (wrv && (k0 + lcol) < K) {
                wv0 = *(const uint4*)(wp + k0);
                wv1 = *(const uint4*)(wp + k0 + 8);
            }
            *(uint4*)&Ws[lrow][lcol]     = wv0;
            *(uint4*)&Ws[lrow][lcol + 8] = wv1;
        }
        __syncthreads();
        #pragma unroll
        for (int kk = 0; kk < 64; kk += 32) {
            bf16x8 af[2], bfr[2];
            #pragma unroll
            for (int i = 0; i < 2; i++) {
                af[i]  = __builtin_bit_cast(bf16x8, *(const uint4*)&As[wm + 16*i + ml][kk + qd*8]);
                bfr[i] = __builtin_bit_cast(bf16x8, *(const uint4*)&Ws[wn + 16*i + ml][kk + qd*8]);
            }
            #pragma unroll
            for (int i = 0; i < 2; i++)
                #pragma unroll
                for (int j = 0; j < 2; j++)
                    acc[i][j] = __builtin_amdgcn_mfma_f32_16x16x32_bf16(af[i], bfr[j], acc[i][j], 0, 0, 0);
        }
        __syncthreads();
    }

    const float* bz = (EPI != 1 && bias) ? bias + (long long)zo * b_zo : nullptr;
    const float* lz = (EPI == 3) ? ls + (long long)zo * ls_zo : nullptr;

    #pragma unroll
    for (int i = 0; i < 2; i++) {
        #pragma unroll
        for (int j = 0; j < 2; j++) {
            const int nn = n0 + wn + 16*j + ml;
            if (nn >= N) continue;
            float bv = 0.f;
            if (EPI != 1 && bz) bv = bz[nn];
            float lsv = 0.f;
            if (EPI == 3) lsv = lz[nn];
            #pragma unroll
            for (int r = 0; r < 4; r++) {
                const int mm = m0 + wm + 16*i + qd*4 + r;
                if (mm >= M) continue;
                float v = acc[i][j][r];
                if (EPI == 0) {
                    u16* C = (u16*)Cv + (long long)zo * c_zo + (long long)zi * c_zi;
                    C[(size_t)mm * ldc + nn] = f2bf(v + bv);
                } else if (EPI == 1) {
                    float* C = (float*)Cv + (long long)zo * c_zo + (long long)zi * c_zi;
                    C[(size_t)mm * ldc + nn] = v * 0.125f;
                } else if (EPI == 2) {
                    u16* C = (u16*)Cv + (long long)zo * c_zo + (long long)zi * c_zi;
                    C[(size_t)nn * ldc + mm] = f2bf(v + bv);
                } else if (EPI == 3) {
                    float* C = (float*)Cv + (long long)zo * c_zo + (long long)zi * c_zi;
                    const size_t idx = (size_t)mm * ldc + nn;
                    C[idx] = C[idx] + lsv * (v + bv);
                } else {
                    u16* C = (u16*)Cv + (long long)zo * c_zo + (long long)zi * c_zi;
                    float x = v + bv;
                    float g = 0.5f * x * (1.f + erff(x * 0.70710678118654752f));
                    C[(size_t)mm * ldc + nn] = f2bf(g);
                }
            }
        }
    }
}

// ---------------------------------------------------------------------------
// LayerNorm over H=1024 per row. INF32: input fp32, else bf16. Output bf16.
// ---------------------------------------------------------------------------
template<int INF32>
__global__ __launch_bounds__(256)
void ln_k(const void* __restrict__ in, u16* __restrict__ out,
          const float* __restrict__ w, const float* __restrict__ b,
          long long wz, int rows_per_e)
{
    const int row = blockIdx.x;
    const int e = row / rows_per_e;
    const int t = threadIdx.x;
    float x[4];
    if (INF32) {
        const float* p = (const float*)in + (size_t)row * 1024;
        #pragma unroll
        for (int j = 0; j < 4; j++) x[j] = p[t + 256*j];
    } else {
        const u16* p = (const u16*)in + (size_t)row * 1024;
        #pragma unroll
        for (int j = 0; j < 4; j++) x[j] = bf2f(p[t + 256*j]);
    }
    float s = x[0] + x[1] + x[2] + x[3];
    s = blockSum(s);
    const float m = s * (1.f / 1024.f);
    float vs = 0.f;
    #pragma unroll
    for (int j = 0; j < 4; j++) { float d = x[j] - m; vs += d * d; }
    vs = blockSum(vs);
    const float rs = rsqrtf(vs * (1.f / 1024.f) + 1e-5f);
    const float* we = w + (long long)e * wz;
    const float* be = b + (long long)e * wz;
    u16* o = out + (size_t)row * 1024;
    #pragma unroll
    for (int j = 0; j < 4; j++) {
        const int h = t + 256*j;
        o[h] = f2bf((x[j] - m) * rs * we[h] + be[h]);
    }
}

// one wave per row softmax: S fp32 [nrows][kl] -> P bf16
__global__ __launch_bounds__(256)
void softmax_k(const float* __restrict__ S, u16* __restrict__ P, int kl, int nrows)
{
    const int r = blockIdx.x * 4 + (threadIdx.x >> 6);
    const int lane = threadIdx.x & 63;
    if (r >= nrows) return;
    const float* s = S + (size_t)r * kl;
    float v[6];
    int cnt = 0;
    float mx = -3.4e38f;
    for (int i = lane; i < kl; i += 64) { float tv = s[i]; v[cnt++] = tv; mx = fmaxf(mx, tv); }
    #pragma unroll
    for (int off = 32; off; off >>= 1) mx = fmaxf(mx, __shfl_xor(mx, off, 64));
    float sum = 0.f;
    for (int i = 0; i < cnt; i++) { v[i] = expf(v[i] - mx); sum += v[i]; }
    #pragma unroll
    for (int off = 32; off; off >>= 1) sum += __shfl_xor(sum, off, 64);
    const float inv = 1.f / sum;
    u16* p = P + (size_t)r * kl;
    cnt = 0;
    for (int i = lane; i < kl; i += 64) p[i] = f2bf(v[cnt++] * inv);
}

// build KV0[e][b][kl][H] (bf16) = [query_slice ; z_window], X fp32 = query_slice
__global__ __launch_bounds__(256)
void prep_k(const float* __restrict__ query, const float* __restrict__ img, const float* __restrict__ prm,
            u16* __restrict__ KV0, float* __restrict__ X,
            int sq, int qo, int io, int kl)
{
    const int idx = blockIdx.x;
    const int e = idx / (8 * kl);
    const int rem = idx - e * 8 * kl;
    const int b = rem / kl;
    const int k = rem - b * kl;
    const int t = threadIdx.x;
    const float* src;
    if (k < sq) src = query + ((size_t)e * 144 + qo + k) * 1024;
    else {
        const int zr = io + (k - sq);
        src = (zr < 576) ? img + ((size_t)b * 576 + zr) * 1024
                         : prm + ((size_t)b * 192 + (zr - 576)) * 1024;
    }
    const float4 d = *(const float4*)(src + t * 4);
    u16* dst = KV0 + (((size_t)(e * 8 + b) * kl) + k) * 1024 + t * 4;
    unsigned p0 = (unsigned)f2bf(d.x) | ((unsigned)f2bf(d.y) << 16);
    unsigned p1 = (unsigned)f2bf(d.z) | ((unsigned)f2bf(d.w) << 16);
    *(uint2*)dst = make_uint2(p0, p1);
    if (k < sq) {
        float* xd = X + (((size_t)(e * 8 + b) * sq) + k) * 1024 + t * 4;
        *(float4*)xd = d;
    }
}

__global__ __launch_bounds__(256)
void copy_y_k(const float* __restrict__ X, u16* __restrict__ Y, int sq, int qoff)
{
    const int idx = blockIdx.x;
    const int e = idx / (8 * sq);
    const int rem = idx - e * 8 * sq;
    const int b = rem / sq;
    const int q = rem - b * sq;
    const int t = threadIdx.x;
    const float* xs = X + (((size_t)(e * 8 + b) * sq) + q) * 1024;
    u16* yd = Y + (((size_t)(e * 8 + b) * 144) + qoff + q) * 1024;
    #pragma unroll
    for (int j = 0; j < 4; j++) { const int h = t + 256*j; yd[h] = f2bf(xs[h]); }
}

// gating: partial-summed image mean ++ task_emb ++ elem_emb -> LN -> logits -> softmax -> top2
__global__ __launch_bounds__(256)
void gate_k(const float* __restrict__ part, const int* __restrict__ tids, const int* __restrict__ eids,
            const float* __restrict__ temb, const float* __restrict__ eemb,
            const float* __restrict__ glw, const float* __restrict__ glb,
            const float* __restrict__ gw, const float* __restrict__ gb,
            float* __restrict__ gates)
{
    const int b = blockIdx.x;
    const int t = threadIdx.x;
    __shared__ float gi[1536];
    for (int h = t; h < 1024; h += 256) {
        float s = 0.f;
        #pragma unroll
        for (int c = 0; c < 32; c++) s += part[((size_t)b * 32 + c) * 1024 + h];
        gi[h] = s * (1.f / 576.f);
    }
    {
        const int ti = tids[b], ei = eids[b];
        gi[1024 + t] = temb[ti * 256 + t];
        gi[1280 + t] = eemb[ei * 256 + t];
    }
    __syncthreads();
    float s = 0.f;
    for (int i = t; i < 1536; i += 256) s += gi[i];
    s = blockSum(s);
    const float m = s * (1.f / 1536.f);
    float vs = 0.f;
    for (int i = t; i < 1536; i += 256) { float d = gi[i] - m; vs += d * d; }
    vs = blockSum(vs);
    const float rs = rsqrtf(vs * (1.f / 1536.f) + 1e-5f);
    __shared__ float logit[4];
    for (int e = 0; e < 4; e++) {
        float p = 0.f;
        for (int i = t; i < 1536; i += 256)
            p += ((gi[i] - m) * rs * glw[i] + glb[i]) * gw[e * 1536 + i];
        p = blockSum(p);
        if (t == 0) logit[e] = p + gb[e];
    }
    __syncthreads();
    if (t == 0) {
        float lg[4], ex[4];
        float mx = -1e30f;
        for (int e = 0; e < 4; e++) { lg[e] = fminf(15.f, fmaxf(-15.f, logit[e])); mx = fmaxf(mx, lg[e]); }
        float sum = 0.f;
        for (int e = 0; e < 4; e++) { ex[e] = expf(lg[e] - mx); sum += ex[e]; }
        for (int e = 0; e < 4; e++) ex[e] /= sum;
        int i1 = 0;
        for (int e = 1; e < 4; e++) if (ex[e] > ex[i1]) i1 = e;
        int i2 = -1;
        for (int e = 0; e < 4; e++) if (e != i1 && (i2 < 0 || ex[e] > ex[i2])) i2 = e;
        const float denom = ex[i1] + ex[i2] + 1e-9f;
        float g[4] = {0.f, 0.f, 0.f, 0.f};
        g[i1] = ex[i1] / denom;
        g[i2] = ex[i2] / denom;
        for (int e = 0; e < 4; e++) gates[b * 4 + e] = g[e];
    }
}

// comb = sum_e gates[b][e]*EO[e][bq][:], RMS-norm, * final_w * output_gain -> fp32 out
__global__ __launch_bounds__(256)
void comb_k(const u16* __restrict__ EO, const float* __restrict__ gates,
            const float* __restrict__ fw, const float* __restrict__ og,
            float* __restrict__ out)
{
    const int bq = blockIdx.x;
    const int b = bq / 144;
    const int t = threadIdx.x;
    float g[4];
    #pragma unroll
    for (int e = 0; e < 4; e++) g[e] = gates[b * 4 + e];
    float c[16];
    float ss = 0.f;
    #pragma unroll
    for (int j = 0; j < 16; j++) {
        const int o = t + 256 * j;
        float v = 0.f;
        #pragma unroll
        for (int e = 0; e < 4; e++)
            v += g[e] * bf2f(EO[((size_t)e * 1152 + bq) * 4096 + o]);
        c[j] = v;
        ss += v * v;
    }
    ss = blockSum(ss);
    const float rs = rsqrtf(ss * (1.f / 4096.f) + 1e-6f);
    #pragma unroll
    for (int j = 0; j < 16; j++) {
        const int o = t + 256 * j;
        out[(size_t)bq * 4096 + o] = c[j] * rs * fw[o] * og[o];
    }
}

extern "C" void kernel_launch(void* const* d_in, const int* in_sizes, int n_in,
                              void* d_out, int out_size, void* d_ws, size_t ws_size,
                              hipStream_t stream)
{
    const float* img  = (const float*)d_in[0];
    const float* prm  = (const float*)d_in[1];
    const int*   tids = (const int*)d_in[2];
    const int*   eids = (const int*)d_in[3];
    const float* query= (const float*)d_in[4];
    const float* ln1w = (const float*)d_in[5];
    const float* ln1b = (const float*)d_in[6];
    const float* lkw  = (const float*)d_in[7];
    const float* lkb  = (const float*)d_in[8];
    const float* aiw  = (const float*)d_in[9];
    const float* aib  = (const float*)d_in[10];
    const float* aow  = (const float*)d_in[11];
    const float* aob  = (const float*)d_in[12];
    const float* ls1  = (const float*)d_in[13];
    const float* ls2  = (const float*)d_in[14];
    const float* l2w  = (const float*)d_in[15];
    const float* l2b  = (const float*)d_in[16];
    const float* fcw  = (const float*)d_in[17];
    const float* fcb  = (const float*)d_in[18];
    const float* pjw  = (const float*)d_in[19];
    const float* pjb  = (const float*)d_in[20];
    const float* opw  = (const float*)d_in[21];
    const float* opb  = (const float*)d_in[22];
    const float* temb = (const float*)d_in[23];
    const float* eemb = (const float*)d_in[24];
    const float* glw  = (const float*)d_in[25];
    const float* glb  = (const float*)d_in[26];
    const float* gww  = (const float*)d_in[27];
    const float* gbb  = (const float*)d_in[28];
    const float* og   = (const float*)d_in[29];
    const float* fwv  = (const float*)d_in[30];
    float* out = (float*)d_out;
    (void)in_sizes; (void)n_in; (void)out_size; (void)ws_size;

    char* ws = (char*)d_ws;
    size_t off = 0;
    auto alloc = [&](size_t bytes) -> char* {
        char* p = ws + off;
        off += (bytes + 255) & ~(size_t)255;
        return p;
    };
    float* GATES = (float*)alloc(128);
    float* IPART = (float*)alloc(1048576);        // 8*32*1024 fp32 partial sums
    u16*  AIWB = (u16*) alloc(50331648);          // attn_in_w bf16
    u16*  AOWB = (u16*) alloc(16777216);          // attn_out_w bf16
    u16*  FCWB = (u16*) alloc(67108864);          // fc_w bf16
    u16*  PJWB = (u16*) alloc(67108864);          // proj_w bf16
    u16*  OPWB = (u16*) alloc(33554432);          // outp_w bf16
    u16*  KV0 = (u16*) alloc(20971520);           // E*B*320*1024 bf16
    u16*  KVN = (u16*) alloc(20971520);           // LN(kv0); reused as P after softmax
    u16*  KP  = (u16*) alloc(20971520);           // K proj [e][b][kl][1024]
    u16*  VT  = (u16*) alloc(20971520);           // V proj transposed [(e,b)][1024][kl]
    float* S  = (float*)alloc(41943040);          // scores fp32 [(e,b,h)][sq][kl]
    u16*  QN  = (u16*) alloc(4194304);            // LN(x); also LN2 output
    u16*  QP  = (u16*) alloc(4194304);            // Q proj
    u16*  AO  = (u16*) alloc(4194304);            // attention output (heads concat)
    float* X  = (float*)alloc(8388608);           // residual stream fp32
    u16*  H4  = (u16*) alloc(16777216);           // MLP hidden bf16
    u16*  Y   = (u16*) alloc(9437184);            // per-expert pooled tokens
    u16*  EO  = (u16*) alloc(37748736);           // expert outputs [e][b*144][4096]

    const long long HH = 1024LL * 1024LL;

    // once-per-launch weight conversion fp32 -> bf16 (identical rounding to the
    // old in-GEMM f2bf; hoisted so it happens 1x instead of M/64x per use)
    cvt_k<<<2048, 256, 0, stream>>>(aiw, AIWB, 25165824LL);
    cvt_k<<<2048, 256, 0, stream>>>(aow, AOWB, 8388608LL);
    cvt_k<<<2048, 256, 0, stream>>>(fcw, FCWB, 33554432LL);
    cvt_k<<<2048, 256, 0, stream>>>(pjw, PJWB, 33554432LL);
    cvt_k<<<2048, 256, 0, stream>>>(opw, OPWB, 16777216LL);

    img_mean_k<<<256, 256, 0, stream>>>(img, IPART);
    gate_k<<<8, 256, 0, stream>>>(IPART, tids, eids, temb, eemb, glw, glb, gww, gbb, GATES);

    const int SQ[3] = {64, 48, 32};
    const int IO[3] = {0, 256, 512};
    const int QO[3] = {0, 64, 112};
    const int KL[3] = {320, 304, 288};

    for (int s = 0; s < 3; s++) {
        const int sq = SQ[s], kl = KL[s], qo = QO[s], io = IO[s];
        const int Msq = 8 * sq;
        const int Mkl = 8 * kl;
        prep_k<<<4 * 8 * kl, 256, 0, stream>>>(query, img, prm, KV0, X, sq, qo, io, kl);
        for (int l = 0; l < 2; l++) {
            ln_k<0><<<4 * 8 * kl, 256, 0, stream>>>(KV0, KVN, lkw + l*1024, lkb + l*1024, 2048, 8 * kl);
            ln_k<1><<<4 * 8 * sq, 256, 0, stream>>>(X,   QN,  ln1w + l*1024, ln1b + l*1024, 2048, 8 * sq);
            // QP = LN(x) @ Wq^T + bq        [z = e]   (Msq = 512/384/256 -> TM=64)
            gemm_big<0,64><<<dim3(8, Msq/64, 4), 256, 0, stream>>>(
                QN, (long long)Msq * 1024, 0, 1024,
                AIWB + (long long)l * 3 * HH, 6 * HH, 0, 1024,
                QP, (long long)Msq * 1024, 0, 1024,
                aib + l * 3072, 6144,
                nullptr, 0, Msq, 1024, 1024, 1);
            // KP = kvn @ Wk^T + bk          [z = e]   (Mkl multiple of 128)
            gemm_big<0,128><<<dim3(8, Mkl/128, 4), 256, 0, stream>>>(
                KVN, (long long)Mkl * 1024, 0, 1024,
                AIWB + (long long)l * 3 * HH + HH, 6 * HH, 0, 1024,
                KP, (long long)Mkl * 1024, 0, 1024,
                aib + l * 3072 + 1024, 6144,
                nullptr, 0, Mkl, 1024, 1024, 1);
            // VT = (kvn @ Wv^T + bv)^T per (e,b)   [z = (e,b), Zi=8], M=kl row-clamped
            gemm_big<2,128><<<dim3(8, (kl + 127)/128, 32), 256, 0, stream>>>(
                KVN, (long long)8 * kl * 1024, (long long)kl * 1024, 1024,
                AIWB + (long long)l * 3 * HH + 2 * HH, 6 * HH, 0, 1024,
                VT, (long long)8 * 1024 * kl, (long long)1024 * kl, kl,
                aib + l * 3072 + 2048, 6144,
                nullptr, 0, kl, 1024, 1024, 8);
            // S = QP KP^T / 8 per (e,b,h)   [z = (e,b,h), Zi=16]  (legacy kernel)
            gemm_k<1,0><<<dim3((kl + 63)/64, 1, 512), 256, 0, stream>>>(
                QP, (long long)sq * 1024, 64, 1024,
                KP, (long long)kl * 1024, 64, 1024,
                S, (long long)16 * sq * kl, (long long)sq * kl, kl,
                nullptr, 0, nullptr, 0, sq, kl, 64, 16);
            {
                const int nrows = 4 * 8 * 16 * sq;
                softmax_k<<<(nrows + 3)/4, 256, 0, stream>>>(S, KVN, kl, nrows);
            }
            // AO = P @ V                    [z = (e,b,h), Zi=16]  (legacy kernel)
            gemm_k<0,0><<<dim3(1, 1, 512), 256, 0, stream>>>(
                KVN, (long long)16 * sq * kl, (long long)sq * kl, kl,
                VT, (long long)1024 * kl, (long long)64 * kl, kl,
                AO, (long long)sq * 1024, 64, 1024,
                nullptr, 0, nullptr, 0, sq, 64, kl, 16);
            // X += ls1 * (AO @ Wo^T + bo)   [z = e]
            gemm_big<3,64><<<dim3(8, Msq/64, 4), 256, 0, stream>>>(
                AO, (long long)Msq * 1024, 0, 1024,
                AOWB + (long long)l * HH, 2 * HH, 0, 1024,
                X, (long long)Msq * 1024, 0, 1024,
                aob + l * 1024, 2048,
                ls1 + l * 1024, 2048,
                Msq, 1024, 1024, 1);
            ln_k<1><<<4 * 8 * sq, 256, 0, stream>>>(X, QN, l2w + l*1024, l2b + l*1024, 2048, 8 * sq);
            // H4 = gelu(QN @ fc^T + b)      [z = e]   (Msq/128 exact: 4/3/2)
            gemm_big<4,128><<<dim3(32, Msq/128, 4), 256, 0, stream>>>(
                QN, (long long)Msq * 1024, 0, 1024,
                FCWB + (long long)l * 4 * HH, 8 * HH, 0, 1024,
                H4, (long long)Msq * 4096, 0, 4096,
                fcb + l * 4096, 8192,
                nullptr, 0, Msq, 4096, 1024, 1);
            // X += ls2 * (H4 @ proj^T + b)  [z = e]
            gemm_big<3,64><<<dim3(8, Msq/64, 4), 256, 0, stream>>>(
                H4, (long long)Msq * 4096, 0, 4096,
                PJWB + (long long)l * 4 * HH, 8 * HH, 0, 4096,
                X, (long long)Msq * 1024, 0, 1024,
                pjb + l * 1024, 2048,
                ls2 + l * 1024, 2048,
                Msq, 1024, 4096, 1);
        }
        copy_y_k<<<4 * 8 * sq, 256, 0, stream>>>(X, Y, sq, qo);
    }
    // EO = Y @ outp_w^T + outp_b            [z = e]
    gemm_big<0,128><<<dim3(32, 9, 4), 256, 0, stream>>>(
        Y, 1152LL * 1024, 0, 1024,
        OPWB, 4096LL * 1024, 0, 1024,
        EO, 1152LL * 4096, 0, 4096,
        opb, 4096,
        nullptr, 0, 1152, 4096, 1024, 1);
    comb_k<<<1152, 256, 0, stream>>>(EO, GATES, fwv, og, out);
}

// Round 2
// 2393.452 us; speedup vs baseline: 1.3433x; 1.2385x over previous
//
#include <hip/hip_runtime.h>

typedef unsigned short u16;
typedef __bf16 bf16x8 __attribute__((ext_vector_type(8)));
typedef float f32x4 __attribute__((ext_vector_type(4)));

typedef const __attribute__((address_space(1))) void* gp1;
typedef __attribute__((address_space(3))) void* lp3;

__device__ __forceinline__ float bf2f(u16 u){
    union { unsigned int i; float f; } v; v.i = ((unsigned int)u) << 16; return v.f;
}
__device__ __forceinline__ u16 f2bf(float f){
    union { float f; unsigned int i; } v; v.f = f;
    unsigned int u = v.i;
    return (u16)((u + 0x7FFFu + ((u >> 16) & 1u)) >> 16);
}

// async global->LDS, 16B per lane. LDS dest must be wave-uniform base; HW adds lane*16.
__device__ __forceinline__ void gload16(const u16* g, const u16* l){
    __builtin_amdgcn_global_load_lds((gp1)(uintptr_t)g, (lp3)(uintptr_t)l, 16, 0, 0);
}

// block-wide sum for blockDim == 256 (4 waves)
__device__ __forceinline__ float blockSum(float v){
    #pragma unroll
    for (int off = 32; off; off >>= 1) v += __shfl_xor(v, off, 64);
    __shared__ float sm[4];
    const int w = threadIdx.x >> 6;
    __syncthreads();
    if ((threadIdx.x & 63) == 0) sm[w] = v;
    __syncthreads();
    return sm[0] + sm[1] + sm[2] + sm[3];
}

// fp32 -> bf16 elementwise (weights, once per launch). n multiple of 8.
__global__ __launch_bounds__(256)
void cvt_k(const float* __restrict__ in, u16* __restrict__ out, long long n)
{
    const long long stride = (long long)gridDim.x * 256 * 8;
    for (long long i = ((long long)blockIdx.x * 256 + threadIdx.x) * 8; i < n; i += stride) {
        float4 a = *(const float4*)(in + i);
        float4 b = *(const float4*)(in + i + 4);
        uint4 o;
        o.x = (unsigned)f2bf(a.x) | ((unsigned)f2bf(a.y) << 16);
        o.y = (unsigned)f2bf(a.z) | ((unsigned)f2bf(a.w) << 16);
        o.z = (unsigned)f2bf(b.x) | ((unsigned)f2bf(b.y) << 16);
        o.w = (unsigned)f2bf(b.z) | ((unsigned)f2bf(b.w) << 16);
        *(uint4*)(out + i) = o;
    }
}

// partial sums of image_embs over rows: grid (8*32), 18 rows each
__global__ __launch_bounds__(256)
void img_mean_k(const float* __restrict__ img, float* __restrict__ part)
{
    const int b = blockIdx.x >> 5, c = blockIdx.x & 31;
    const int t = threadIdx.x;
    const float* p = img + ((size_t)b * 576 + (size_t)c * 18) * 1024 + t * 4;
    float4 s = make_float4(0.f, 0.f, 0.f, 0.f);
    #pragma unroll
    for (int r = 0; r < 18; r++) {
        float4 v = *(const float4*)(p + (size_t)r * 1024);
        s.x += v.x; s.y += v.y; s.z += v.z; s.w += v.w;
    }
    *(float4*)(part + (size_t)blockIdx.x * 1024 + t * 4) = s;
}

// ---------------------------------------------------------------------------
// GEMM v2: tile TM x 128, BK=64, 2-phase double-buffered global_load_lds
// staging with XOR bank-swizzle (pre-swizzled global source col; LDS dest
// stays linear per m104/m173; ds_read applies the same XOR).
// EPI: 0 bf16 +bias | 3 fp32 RMW += ls*(acc+bias) | 4 bf16 exact-GELU +bias
//      5 fused K/V: nn<1024 -> KP (normal), nn>=1024 -> VT (transposed);
//        kl passed via c_zi, VT base via ls, VT z-stride via ls_zo.
// K multiple of 64; M,N multiples of tile except EPI<5 row-clamp on stage.
// ---------------------------------------------------------------------------
template<int EPI, int TM>
__global__ __launch_bounds__(256)
void gemm_big(const u16* __restrict__ A, long long a_zo, long long a_zi, int lda,
              const u16* __restrict__ W, long long w_zo, long long w_zi, int ldw,
              void* __restrict__ Cv, long long c_zo, long long c_zi, int ldc,
              const float* __restrict__ bias, long long b_zo,
              const float* __restrict__ ls, long long ls_zo,
              int M, int N, int K, int Zi)
{
    constexpr int MI = TM / 32;          // 16x16 A-fragments per wave in M
    __shared__ u16 As[2][TM * 64];
    __shared__ u16 Ws[2][128 * 64];
    const int z  = blockIdx.z;
    const int zo = z / Zi, zi = z - zo * Zi;
    const u16* Az = A + (long long)zo * a_zo + (long long)zi * a_zi;
    const u16* Wz = W + (long long)zo * w_zo + (long long)zi * w_zi;
    const int m0 = blockIdx.y * TM, n0 = blockIdx.x * 128;
    const int t = threadIdx.x;
    const int lane = t & 63, wid = t >> 6;
    const int wm = (wid >> 1) * (TM / 2), wn = (wid & 1) * 64;
    const int qd = lane >> 4, ml = lane & 15;
    // staging: lane covers LDS row (t>>3)&7 within its wave's 8-row stripe.
    // Pre-swizzled global col: chunk (t&7) ^ (row&7)  (T2 via m173 pattern).
    const int srow = t >> 3;
    const int scol = (((t & 7) ^ (srow & 7)) << 3);

    f32x4 acc[MI][4];
    #pragma unroll
    for (int i = 0; i < MI; i++)
        #pragma unroll
        for (int j = 0; j < 4; j++) acc[i][j] = (f32x4){0.f, 0.f, 0.f, 0.f};

    int arow[MI];
    #pragma unroll
    for (int i = 0; i < MI; i++) {
        int r = m0 + i * 32 + srow; arow[i] = (r < M) ? r : (M - 1);
    }
    int wrow[4];
    #pragma unroll
    for (int i = 0; i < 4; i++) {
        int r = n0 + i * 32 + srow; wrow[i] = (r < N) ? r : (N - 1);
    }

    auto stage = [&](int buf, int k0){
        #pragma unroll
        for (int i = 0; i < MI; i++)
            gload16(Az + (size_t)arow[i] * lda + k0 + scol, &As[buf][(i * 32 + wid * 8) * 64]);
        #pragma unroll
        for (int i = 0; i < 4; i++)
            gload16(Wz + (size_t)wrow[i] * ldw + k0 + scol, &Ws[buf][(i * 32 + wid * 8) * 64]);
    };

    const int NT = K >> 6;
    stage(0, 0);
    __syncthreads();                       // drain prologue loads
    for (int it = 0; it < NT; ++it) {
        if (it + 1 < NT) stage((it + 1) & 1, (it + 1) << 6);   // prefetch next tile
        const u16* Ab = As[it & 1];
        const u16* Wb = Ws[it & 1];
        #pragma unroll
        for (int kk = 0; kk < 64; kk += 32) {
            bf16x8 af[MI], bfr[4];
            #pragma unroll
            for (int i = 0; i < MI; i++) {
                const int row = wm + 16 * i + ml;
                const int ch  = (((qd + (kk >> 3)) ^ (ml & 7)) << 3);
                af[i] = __builtin_bit_cast(bf16x8, *(const uint4*)&Ab[row * 64 + ch]);
            }
            #pragma unroll
            for (int j = 0; j < 4; j++) {
                const int row = wn + 16 * j + ml;
                const int ch  = (((qd + (kk >> 3)) ^ (ml & 7)) << 3);
                bfr[j] = __builtin_bit_cast(bf16x8, *(const uint4*)&Wb[row * 64 + ch]);
            }
            #pragma unroll
            for (int i = 0; i < MI; i++)
                #pragma unroll
                for (int j = 0; j < 4; j++)
                    acc[i][j] = __builtin_amdgcn_mfma_f32_16x16x32_bf16(af[i], bfr[j], acc[i][j], 0, 0, 0);
        }
        __syncthreads();                   // drains prefetch vmcnt + this tile's lgkm
    }

    const float* bz = bias ? bias + (long long)zo * b_zo : nullptr;
    const float* lz = (EPI == 3) ? ls + (long long)zo * ls_zo : nullptr;
    const long long coff = (long long)zo * c_zo + (long long)zi * c_zi;

    if (EPI == 5) {
        const int klv = (int)c_zi;
        u16* KPz = (u16*)Cv + (long long)zo * c_zo;
        u16* VTz = (u16*)(uintptr_t)(const void*)ls + (long long)zo * ls_zo;
        #pragma unroll
        for (int i = 0; i < MI; i++) {
            #pragma unroll
            for (int j = 0; j < 4; j++) {
                const int nn = n0 + wn + 16 * j + ml;
                const float bv = bz[nn];
                const int mmb = m0 + wm + 16 * i + qd * 4;   // M,N exact multiples here
                if (nn < 1024) {
                    #pragma unroll
                    for (int r = 0; r < 4; r++)
                        KPz[(size_t)(mmb + r) * ldc + nn] = f2bf(acc[i][j][r] + bv);
                } else {
                    const int b = mmb / klv;                 // kl%4==0 -> no straddle
                    const int k = mmb - b * klv;
                    u16 tmp[4];
                    #pragma unroll
                    for (int r = 0; r < 4; r++) tmp[r] = f2bf(acc[i][j][r] + bv);
                    u16* p = VTz + ((size_t)(b * 1024 + (nn - 1024))) * klv + k;
                    *(uint2*)p = make_uint2((unsigned)tmp[0] | ((unsigned)tmp[1] << 16),
                                            (unsigned)tmp[2] | ((unsigned)tmp[3] << 16));
                }
            }
        }
        return;
    }

    #pragma unroll
    for (int i = 0; i < MI; i++) {
        #pragma unroll
        for (int j = 0; j < 4; j++) {
            const int nn = n0 + wn + 16 * j + ml;
            if (nn >= N) continue;
            const float bv = bz ? bz[nn] : 0.f;
            const float lsv = (EPI == 3) ? lz[nn] : 0.f;
            #pragma unroll
            for (int r = 0; r < 4; r++) {
                const int mm = m0 + wm + 16 * i + qd * 4 + r;
                if (mm >= M) continue;
                float v = acc[i][j][r];
                if (EPI == 0) {
                    ((u16*)Cv + coff)[(size_t)mm * ldc + nn] = f2bf(v + bv);
                } else if (EPI == 3) {
                    float* C = (float*)Cv + coff;
                    const size_t idx = (size_t)mm * ldc + nn;
                    C[idx] = C[idx] + lsv * (v + bv);
                } else { // EPI == 4
                    float x = v + bv;
                    float g = 0.5f * x * (1.f + erff(x * 0.70710678118654752f));
                    ((u16*)Cv + coff)[(size_t)mm * ldc + nn] = f2bf(g);
                }
            }
        }
    }
}

// ---------------------------------------------------------------------------
// Legacy 64x64 GEMM — kept for the small attention GEMMs (S = QK^T, AO = P@V).
// ---------------------------------------------------------------------------
template<int EPI, int WF32>
__global__ __launch_bounds__(256)
void gemm_k(const u16* __restrict__ A, long long a_zo, long long a_zi, int lda,
            const void* __restrict__ W, long long w_zo, long long w_zi, int ldw,
            void* __restrict__ Cv, long long c_zo, long long c_zi, int ldc,
            const float* __restrict__ bias, long long b_zo,
            const float* __restrict__ ls, long long ls_zo,
            int M, int N, int K, int Zi)
{
    __shared__ u16 As[64][72];
    __shared__ u16 Ws[64][72];
    const int z  = blockIdx.z;
    const int zo = z / Zi, zi = z - zo * Zi;
    const u16* Az = A + (long long)zo * a_zo + (long long)zi * a_zi;
    const long long wbase = (long long)zo * w_zo + (long long)zi * w_zi;
    const int m0 = blockIdx.y * 64, n0 = blockIdx.x * 64;
    const int t = threadIdx.x;
    const int lrow = t >> 2, lcol = (t & 3) * 16;
    const int lane = t & 63, wid = t >> 6;
    const int wm = (wid >> 1) * 32, wn = (wid & 1) * 32;
    const int qd = lane >> 4, ml = lane & 15;

    f32x4 acc[2][2];
    #pragma unroll
    for (int i = 0; i < 2; i++)
        #pragma unroll
        for (int j = 0; j < 2; j++) acc[i][j] = (f32x4){0.f, 0.f, 0.f, 0.f};

    const bool arv = (m0 + lrow) < M;
    const bool wrv = (n0 + lrow) < N;
    const u16* ap = Az + (size_t)(m0 + lrow) * lda + lcol;

    for (int k0 = 0; k0 < K; k0 += 64) {
        {
            uint4 av0 = make_uint4(0u,0u,0u,0u), av1 = make_uint4(0u,0u,0u,0u);
            if (arv && (k0 + lcol) < K) {
                av0 = *(const uint4*)(ap + k0);
                av1 = *(const uint4*)(ap + k0 + 8);
            }
            *(uint4*)&As[lrow][lcol]     = av0;
            *(uint4*)&As[lrow][lcol + 8] = av1;
        }
        {
            const u16* wp = (const u16*)W + wbase + (size_t)(n0 + lrow) * ldw + lcol;
            uint4 wv0 = make_uint4(0u,0u,0u,0u), wv1 = make_uint4(0u,0u,0u,0u);
            if (wrv && (k0 + lcol) < K) {
                wv0 = *(const uint4*)(wp + k0);
                wv1 = *(const uint4*)(wp + k0 + 8);
            }
            *(uint4*)&Ws[lrow][lcol]     = wv0;
            *(uint4*)&Ws[lrow][lcol + 8] = wv1;
        }
        __syncthreads();
        #pragma unroll
        for (int kk = 0; kk < 64; kk += 32) {
            bf16x8 af[2], bfr[2];
            #pragma unroll
            for (int i = 0; i < 2; i++) {
                af[i]  = __builtin_bit_cast(bf16x8, *(const uint4*)&As[wm + 16*i + ml][kk + qd*8]);
                bfr[i] = __builtin_bit_cast(bf16x8, *(const uint4*)&Ws[wn + 16*i + ml][kk + qd*8]);
            }
            #pragma unroll
            for (int i = 0; i < 2; i++)
                #pragma unroll
                for (int j = 0; j < 2; j++)
                    acc[i][j] = __builtin_amdgcn_mfma_f32_16x16x32_bf16(af[i], bfr[j], acc[i][j], 0, 0, 0);
        }
        __syncthreads();
    }

    #pragma unroll
    for (int i = 0; i < 2; i++) {
        #pragma unroll
        for (int j = 0; j < 2; j++) {
            const int nn = n0 + wn + 16*j + ml;
            if (nn >= N) continue;
            #pragma unroll
            for (int r = 0; r < 4; r++) {
                const int mm = m0 + wm + 16*i + qd*4 + r;
                if (mm >= M) continue;
                float v = acc[i][j][r];
                if (EPI == 1) {
                    float* C = (float*)Cv + (long long)zo * c_zo + (long long)zi * c_zi;
                    C[(size_t)mm * ldc + nn] = v * 0.125f;
                } else {
                    u16* C = (u16*)Cv + (long long)zo * c_zo + (long long)zi * c_zi;
                    C[(size_t)mm * ldc + nn] = f2bf(v);
                }
            }
        }
    }
}

// ---------------------------------------------------------------------------
// LayerNorm over H=1024 per row. INF32: input fp32, else bf16. Output bf16.
// ---------------------------------------------------------------------------
template<int INF32>
__global__ __launch_bounds__(256)
void ln_k(const void* __restrict__ in, u16* __restrict__ out,
          const float* __restrict__ w, const float* __restrict__ b,
          long long wz, int rows_per_e)
{
    const int row = blockIdx.x;
    const int e = row / rows_per_e;
    const int t = threadIdx.x;
    float x[4];
    if (INF32) {
        const float* p = (const float*)in + (size_t)row * 1024;
        #pragma unroll
        for (int j = 0; j < 4; j++) x[j] = p[t + 256*j];
    } else {
        const u16* p = (const u16*)in + (size_t)row * 1024;
        #pragma unroll
        for (int j = 0; j < 4; j++) x[j] = bf2f(p[t + 256*j]);
    }
    float s = x[0] + x[1] + x[2] + x[3];
    s = blockSum(s);
    const float m = s * (1.f / 1024.f);
    float vs = 0.f;
    #pragma unroll
    for (int j = 0; j < 4; j++) { float d = x[j] - m; vs += d * d; }
    vs = blockSum(vs);
    const float rs = rsqrtf(vs * (1.f / 1024.f) + 1e-5f);
    const float* we = w + (long long)e * wz;
    const float* be = b + (long long)e * wz;
    u16* o = out + (size_t)row * 1024;
    #pragma unroll
    for (int j = 0; j < 4; j++) {
        const int h = t + 256*j;
        o[h] = f2bf((x[j] - m) * rs * we[h] + be[h]);
    }
}

// one wave per row softmax: S fp32 [nrows][kl] -> P bf16
__global__ __launch_bounds__(256)
void softmax_k(const float* __restrict__ S, u16* __restrict__ P, int kl, int nrows)
{
    const int r = blockIdx.x * 4 + (threadIdx.x >> 6);
    const int lane = threadIdx.x & 63;
    if (r >= nrows) return;
    const float* s = S + (size_t)r * kl;
    float v[6];
    int cnt = 0;
    float mx = -3.4e38f;
    for (int i = lane; i < kl; i += 64) { float tv = s[i]; v[cnt++] = tv; mx = fmaxf(mx, tv); }
    #pragma unroll
    for (int off = 32; off; off >>= 1) mx = fmaxf(mx, __shfl_xor(mx, off, 64));
    float sum = 0.f;
    for (int i = 0; i < cnt; i++) { v[i] = expf(v[i] - mx); sum += v[i]; }
    #pragma unroll
    for (int off = 32; off; off >>= 1) sum += __shfl_xor(sum, off, 64);
    const float inv = 1.f / sum;
    u16* p = P + (size_t)r * kl;
    cnt = 0;
    for (int i = lane; i < kl; i += 64) p[i] = f2bf(v[cnt++] * inv);
}

// build KV0[e][b][kl][H] (bf16) = [query_slice ; z_window], X fp32 = query_slice
__global__ __launch_bounds__(256)
void prep_k(const float* __restrict__ query, const float* __restrict__ img, const float* __restrict__ prm,
            u16* __restrict__ KV0, float* __restrict__ X,
            int sq, int qo, int io, int kl)
{
    const int idx = blockIdx.x;
    const int e = idx / (8 * kl);
    const int rem = idx - e * 8 * kl;
    const int b = rem / kl;
    const int k = rem - b * kl;
    const int t = threadIdx.x;
    const float* src;
    if (k < sq) src = query + ((size_t)e * 144 + qo + k) * 1024;
    else {
        const int zr = io + (k - sq);
        src = (zr < 576) ? img + ((size_t)b * 576 + zr) * 1024
                         : prm + ((size_t)b * 192 + (zr - 576)) * 1024;
    }
    const float4 d = *(const float4*)(src + t * 4);
    u16* dst = KV0 + (((size_t)(e * 8 + b) * kl) + k) * 1024 + t * 4;
    unsigned p0 = (unsigned)f2bf(d.x) | ((unsigned)f2bf(d.y) << 16);
    unsigned p1 = (unsigned)f2bf(d.z) | ((unsigned)f2bf(d.w) << 16);
    *(uint2*)dst = make_uint2(p0, p1);
    if (k < sq) {
        float* xd = X + (((size_t)(e * 8 + b) * sq) + k) * 1024 + t * 4;
        *(float4*)xd = d;
    }
}

__global__ __launch_bounds__(256)
void copy_y_k(const float* __restrict__ X, u16* __restrict__ Y, int sq, int qoff)
{
    const int idx = blockIdx.x;
    const int e = idx / (8 * sq);
    const int rem = idx - e * 8 * sq;
    const int b = rem / sq;
    const int q = rem - b * sq;
    const int t = threadIdx.x;
    const float* xs = X + (((size_t)(e * 8 + b) * sq) + q) * 1024;
    u16* yd = Y + (((size_t)(e * 8 + b) * 144) + qoff + q) * 1024;
    #pragma unroll
    for (int j = 0; j < 4; j++) { const int h = t + 256*j; yd[h] = f2bf(xs[h]); }
}

// gating: partial-summed image mean ++ task_emb ++ elem_emb -> LN -> logits -> softmax -> top2
__global__ __launch_bounds__(256)
void gate_k(const float* __restrict__ part, const int* __restrict__ tids, const int* __restrict__ eids,
            const float* __restrict__ temb, const float* __restrict__ eemb,
            const float* __restrict__ glw, const float* __restrict__ glb,
            const float* __restrict__ gw, const float* __restrict__ gb,
            float* __restrict__ gates)
{
    const int b = blockIdx.x;
    const int t = threadIdx.x;
    __shared__ float gi[1536];
    for (int h = t; h < 1024; h += 256) {
        float s = 0.f;
        #pragma unroll
        for (int c = 0; c < 32; c++) s += part[((size_t)b * 32 + c) * 1024 + h];
        gi[h] = s * (1.f / 576.f);
    }
    {
        const int ti = tids[b], ei = eids[b];
        gi[1024 + t] = temb[ti * 256 + t];
        gi[1280 + t] = eemb[ei * 256 + t];
    }
    __syncthreads();
    float s = 0.f;
    for (int i = t; i < 1536; i += 256) s += gi[i];
    s = blockSum(s);
    const float m = s * (1.f / 1536.f);
    float vs = 0.f;
    for (int i = t; i < 1536; i += 256) { float d = gi[i] - m; vs += d * d; }
    vs = blockSum(vs);
    const float rs = rsqrtf(vs * (1.f / 1536.f) + 1e-5f);
    __shared__ float logit[4];
    for (int e = 0; e < 4; e++) {
        float p = 0.f;
        for (int i = t; i < 1536; i += 256)
            p += ((gi[i] - m) * rs * glw[i] + glb[i]) * gw[e * 1536 + i];
        p = blockSum(p);
        if (t == 0) logit[e] = p + gb[e];
    }
    __syncthreads();
    if (t == 0) {
        float lg[4], ex[4];
        float mx = -1e30f;
        for (int e = 0; e < 4; e++) { lg[e] = fminf(15.f, fmaxf(-15.f, logit[e])); mx = fmaxf(mx, lg[e]); }
        float sum = 0.f;
        for (int e = 0; e < 4; e++) { ex[e] = expf(lg[e] - mx); sum += ex[e]; }
        for (int e = 0; e < 4; e++) ex[e] /= sum;
        int i1 = 0;
        for (int e = 1; e < 4; e++) if (ex[e] > ex[i1]) i1 = e;
        int i2 = -1;
        for (int e = 0; e < 4; e++) if (e != i1 && (i2 < 0 || ex[e] > ex[i2])) i2 = e;
        const float denom = ex[i1] + ex[i2] + 1e-9f;
        float g[4] = {0.f, 0.f, 0.f, 0.f};
        g[i1] = ex[i1] / denom;
        g[i2] = ex[i2] / denom;
        for (int e = 0; e < 4; e++) gates[b * 4 + e] = g[e];
    }
}

// comb = sum_e gates[b][e]*EO[e][bq][:], RMS-norm, * final_w * output_gain -> fp32 out
__global__ __launch_bounds__(256)
void comb_k(const u16* __restrict__ EO, const float* __restrict__ gates,
            const float* __restrict__ fw, const float* __restrict__ og,
            float* __restrict__ out)
{
    const int bq = blockIdx.x;
    const int b = bq / 144;
    const int t = threadIdx.x;
    float g[4];
    #pragma unroll
    for (int e = 0; e < 4; e++) g[e] = gates[b * 4 + e];
    float c[16];
    float ss = 0.f;
    #pragma unroll
    for (int j = 0; j < 16; j++) {
        const int o = t + 256 * j;
        float v = 0.f;
        #pragma unroll
        for (int e = 0; e < 4; e++)
            v += g[e] * bf2f(EO[((size_t)e * 1152 + bq) * 4096 + o]);
        c[j] = v;
        ss += v * v;
    }
    ss = blockSum(ss);
    const float rs = rsqrtf(ss * (1.f / 4096.f) + 1e-6f);
    #pragma unroll
    for (int j = 0; j < 16; j++) {
        const int o = t + 256 * j;
        out[(size_t)bq * 4096 + o] = c[j] * rs * fw[o] * og[o];
    }
}

extern "C" void kernel_launch(void* const* d_in, const int* in_sizes, int n_in,
                              void* d_out, int out_size, void* d_ws, size_t ws_size,
                              hipStream_t stream)
{
    const float* img  = (const float*)d_in[0];
    const float* prm  = (const float*)d_in[1];
    const int*   tids = (const int*)d_in[2];
    const int*   eids = (const int*)d_in[3];
    const float* query= (const float*)d_in[4];
    const float* ln1w = (const float*)d_in[5];
    const float* ln1b = (const float*)d_in[6];
    const float* lkw  = (const float*)d_in[7];
    const float* lkb  = (const float*)d_in[8];
    const float* aiw  = (const float*)d_in[9];
    const float* aib  = (const float*)d_in[10];
    const float* aow  = (const float*)d_in[11];
    const float* aob  = (const float*)d_in[12];
    const float* ls1  = (const float*)d_in[13];
    const float* ls2  = (const float*)d_in[14];
    const float* l2w  = (const float*)d_in[15];
    const float* l2b  = (const float*)d_in[16];
    const float* fcw  = (const float*)d_in[17];
    const float* fcb  = (const float*)d_in[18];
    const float* pjw  = (const float*)d_in[19];
    const float* pjb  = (const float*)d_in[20];
    const float* opw  = (const float*)d_in[21];
    const float* opb  = (const float*)d_in[22];
    const float* temb = (const float*)d_in[23];
    const float* eemb = (const float*)d_in[24];
    const float* glw  = (const float*)d_in[25];
    const float* glb  = (const float*)d_in[26];
    const float* gww  = (const float*)d_in[27];
    const float* gbb  = (const float*)d_in[28];
    const float* og   = (const float*)d_in[29];
    const float* fwv  = (const float*)d_in[30];
    float* out = (float*)d_out;
    (void)in_sizes; (void)n_in; (void)out_size; (void)ws_size;

    char* ws = (char*)d_ws;
    size_t off = 0;
    auto alloc = [&](size_t bytes) -> char* {
        char* p = ws + off;
        off += (bytes + 255) & ~(size_t)255;
        return p;
    };
    float* GATES = (float*)alloc(128);
    float* IPART = (float*)alloc(1048576);        // 8*32*1024 fp32 partial sums
    u16*  AIWB = (u16*) alloc(50331648);          // attn_in_w bf16
    u16*  AOWB = (u16*) alloc(16777216);          // attn_out_w bf16
    u16*  FCWB = (u16*) alloc(67108864);          // fc_w bf16
    u16*  PJWB = (u16*) alloc(67108864);          // proj_w bf16
    u16*  OPWB = (u16*) alloc(33554432);          // outp_w bf16
    u16*  KV0 = (u16*) alloc(20971520);           // E*B*320*1024 bf16
    u16*  KVN = (u16*) alloc(20971520);           // LN(kv0); reused as P after softmax
    u16*  KP  = (u16*) alloc(20971520);           // K proj [e][b][kl][1024]
    u16*  VT  = (u16*) alloc(20971520);           // V proj transposed [(e,b)][1024][kl]
    float* S  = (float*)alloc(41943040);          // scores fp32 [(e,b,h)][sq][kl]
    u16*  QN  = (u16*) alloc(4194304);            // LN(x); also LN2 output
    u16*  QP  = (u16*) alloc(4194304);            // Q proj
    u16*  AO  = (u16*) alloc(4194304);            // attention output (heads concat)
    float* X  = (float*)alloc(8388608);           // residual stream fp32
    u16*  H4  = (u16*) alloc(16777216);           // MLP hidden bf16
    u16*  Y   = (u16*) alloc(9437184);            // per-expert pooled tokens
    u16*  EO  = (u16*) alloc(37748736);           // expert outputs [e][b*144][4096]

    const long long HH = 1024LL * 1024LL;

    cvt_k<<<2048, 256, 0, stream>>>(aiw, AIWB, 25165824LL);
    cvt_k<<<2048, 256, 0, stream>>>(aow, AOWB, 8388608LL);
    cvt_k<<<2048, 256, 0, stream>>>(fcw, FCWB, 33554432LL);
    cvt_k<<<2048, 256, 0, stream>>>(pjw, PJWB, 33554432LL);
    cvt_k<<<2048, 256, 0, stream>>>(opw, OPWB, 16777216LL);

    img_mean_k<<<256, 256, 0, stream>>>(img, IPART);
    gate_k<<<8, 256, 0, stream>>>(IPART, tids, eids, temb, eemb, glw, glb, gww, gbb, GATES);

    const int SQ[3] = {64, 48, 32};
    const int IO[3] = {0, 256, 512};
    const int QO[3] = {0, 64, 112};
    const int KL[3] = {320, 304, 288};

    for (int s = 0; s < 3; s++) {
        const int sq = SQ[s], kl = KL[s], qo = QO[s], io = IO[s];
        const int Msq = 8 * sq;
        const int Mkl = 8 * kl;
        prep_k<<<4 * 8 * kl, 256, 0, stream>>>(query, img, prm, KV0, X, sq, qo, io, kl);
        for (int l = 0; l < 2; l++) {
            ln_k<0><<<4 * 8 * kl, 256, 0, stream>>>(KV0, KVN, lkw + l*1024, lkb + l*1024, 2048, 8 * kl);
            ln_k<1><<<4 * 8 * sq, 256, 0, stream>>>(X,   QN,  ln1w + l*1024, ln1b + l*1024, 2048, 8 * sq);
            // QP = LN(x) @ Wq^T + bq        [z = e]
            gemm_big<0,64><<<dim3(8, Msq/64, 4), 256, 0, stream>>>(
                QN, (long long)Msq * 1024, 0, 1024,
                AIWB + (long long)l * 3 * HH, 6 * HH, 0, 1024,
                QP, (long long)Msq * 1024, 0, 1024,
                aib + l * 3072, 6144,
                nullptr, 0, Msq, 1024, 1024, 1);
            // fused K+V: N=2048 over [Wk;Wv]; nn<1024 -> KP, nn>=1024 -> VT^T
            gemm_big<5,128><<<dim3(16, Mkl/128, 4), 256, 0, stream>>>(
                KVN, (long long)Mkl * 1024, 0, 1024,
                AIWB + (long long)l * 3 * HH + HH, 6 * HH, 0, 1024,
                KP, (long long)Mkl * 1024, /*kl via c_zi*/ (long long)kl, 1024,
                aib + l * 3072 + 1024, 6144,
                (const float*)VT, (long long)8 * 1024 * kl,
                Mkl, 2048, 1024, 1);
            // S = QP KP^T / 8 per (e,b,h)   [z = (e,b,h), Zi=16]
            gemm_k<1,0><<<dim3((kl + 63)/64, 1, 512), 256, 0, stream>>>(
                QP, (long long)sq * 1024, 64, 1024,
                KP, (long long)kl * 1024, 64, 1024,
                S, (long long)16 * sq * kl, (long long)sq * kl, kl,
                nullptr, 0, nullptr, 0, sq, kl, 64, 16);
            {
                const int nrows = 4 * 8 * 16 * sq;
                softmax_k<<<(nrows + 3)/4, 256, 0, stream>>>(S, KVN, kl, nrows);
            }
            // AO = P @ V                    [z = (e,b,h), Zi=16]
            gemm_k<0,0><<<dim3(1, 1, 512), 256, 0, stream>>>(
                KVN, (long long)16 * sq * kl, (long long)sq * kl, kl,
                VT, (long long)1024 * kl, (long long)64 * kl, kl,
                AO, (long long)sq * 1024, 64, 1024,
                nullptr, 0, nullptr, 0, sq, 64, kl, 16);
            // X += ls1 * (AO @ Wo^T + bo)   [z = e]
            gemm_big<3,64><<<dim3(8, Msq/64, 4), 256, 0, stream>>>(
                AO, (long long)Msq * 1024, 0, 1024,
                AOWB + (long long)l * HH, 2 * HH, 0, 1024,
                X, (long long)Msq * 1024, 0, 1024,
                aob + l * 1024, 2048,
                ls1 + l * 1024, 2048,
                Msq, 1024, 1024, 1);
            ln_k<1><<<4 * 8 * sq, 256, 0, stream>>>(X, QN, l2w + l*1024, l2b + l*1024, 2048, 8 * sq);
            // H4 = gelu(QN @ fc^T + b)      [z = e]
            gemm_big<4,128><<<dim3(32, Msq/128, 4), 256, 0, stream>>>(
                QN, (long long)Msq * 1024, 0, 1024,
                FCWB + (long long)l * 4 * HH, 8 * HH, 0, 1024,
                H4, (long long)Msq * 4096, 0, 4096,
                fcb + l * 4096, 8192,
                nullptr, 0, Msq, 4096, 1024, 1);
            // X += ls2 * (H4 @ proj^T + b)  [z = e]
            gemm_big<3,64><<<dim3(8, Msq/64, 4), 256, 0, stream>>>(
                H4, (long long)Msq * 4096, 0, 4096,
                PJWB + (long long)l * 4 * HH, 8 * HH, 0, 4096,
                X, (long long)Msq * 1024, 0, 1024,
                pjb + l * 1024, 2048,
                ls2 + l * 1024, 2048,
                Msq, 1024, 4096, 1);
        }
        copy_y_k<<<4 * 8 * sq, 256, 0, stream>>>(X, Y, sq, qo);
    }
    // EO = Y @ outp_w^T + outp_b            [z = e]
    gemm_big<0,128><<<dim3(32, 9, 4), 256, 0, stream>>>(
        Y, 1152LL * 1024, 0, 1024,
        OPWB, 4096LL * 1024, 0, 1024,
        EO, 1152LL * 4096, 0, 4096,
        opb, 4096,
        nullptr, 0, 1152, 4096, 1024, 1);
    comb_k<<<1152, 256, 0, stream>>>(EO, GATES, fwv, og, out);
}